// Round 1
// baseline (455.007 us; speedup 1.0000x reference)
//
#include <hip/hip_runtime.h>
#include <cstddef>

#define NB 64
#define NQ 64
#define NK 8192
#define ND 64

__constant__ float kEpsDummy; // (unused; eps inlined)

// ---------------------------------------------------------------------------
// Kernel 1: per (b, key-tile). One thread owns one key column k:
//   s[q] = dot(query[b,q,:], key[b,k,:])  (64 logits in registers)
//   p[q] = softmax over q of s[q]/8
//   attn[b,q,k] = p[q]  (unnormalized-over-k, fixed up by kernel 2)
//   rowsum[b,q] += p[q] (wave-reduced, one atomic per wave per q)
// ---------------------------------------------------------------------------
__global__ __launch_bounds__(256) void k_qk_softmax(
    const float* __restrict__ query,
    const float* __restrict__ key,
    float* __restrict__ attn,
    float* __restrict__ rowsum)
{
    const int b = blockIdx.y;
    const int k = blockIdx.x * 256 + threadIdx.x;

    const float* __restrict__ qb = query + (size_t)b * NQ * ND;
    const float* __restrict__ kr = key + ((size_t)b * NK + k) * ND;

    float s[NQ];
#pragma unroll
    for (int q = 0; q < NQ; ++q) s[q] = 0.f;

    // Query accesses are wave-uniform (qb uniform, q static, d0 uniform) ->
    // compiler emits scalar loads; keys are per-thread float4 loads.
    for (int d0 = 0; d0 < ND; d0 += 4) {
        const float4 kv = *reinterpret_cast<const float4*>(kr + d0);
#pragma unroll
        for (int q = 0; q < NQ; ++q) {
            const float4 qv = *reinterpret_cast<const float4*>(qb + q * ND + d0);
            s[q] = fmaf(kv.x, qv.x, s[q]);
            s[q] = fmaf(kv.y, qv.y, s[q]);
            s[q] = fmaf(kv.z, qv.z, s[q]);
            s[q] = fmaf(kv.w, qv.w, s[q]);
        }
    }

    // softmax over q (logits are s/8; fold the 1/sqrt(64) into the exp arg)
    float m = s[0];
#pragma unroll
    for (int q = 1; q < NQ; ++q) m = fmaxf(m, s[q]);
    float sum = 0.f;
#pragma unroll
    for (int q = 0; q < NQ; ++q) {
        s[q] = __expf((s[q] - m) * 0.125f);
        sum += s[q];
    }
    const float inv = 1.f / sum;

    float* __restrict__ arow = attn + (size_t)b * NQ * NK + k;
#pragma unroll
    for (int q = 0; q < NQ; ++q) {
        const float p = s[q] * inv;
        arow[(size_t)q * NK] = p;   // coalesced across lanes
        float v = p;
#pragma unroll
        for (int off = 32; off > 0; off >>= 1) v += __shfl_xor(v, off, 64);
        if ((threadIdx.x & 63) == 0) atomicAdd(&rowsum[b * NQ + q], v);
    }
}

// ---------------------------------------------------------------------------
// Kernel 2: per (b, 512-key tile).
//   - load attn tile, scale by 1/(rowsum+eps), write back (final attn output)
//   - accumulate out[b,q,:] += sum_k p_hat[q,k] * value[b,k,:] via LDS tiles,
//     atomicAdd partial 64x64 result into zero-initialized out.
// ---------------------------------------------------------------------------
#define KT 512
__global__ __launch_bounds__(256) void k_scale_pv(
    const float* __restrict__ value,
    const float* __restrict__ rowsum,
    float* __restrict__ attn,
    float* __restrict__ out)
{
    __shared__ float Ps[64][65];   // [q][kk], +1 pad breaks q-strided read conflicts
    __shared__ float Vs[64][64];   // [kk][d]
    __shared__ float invs[NQ];

    const int b  = blockIdx.y;
    const int k0 = blockIdx.x * KT;
    const int tid = threadIdx.x;

    if (tid < NQ) invs[tid] = 1.f / (rowsum[b * NQ + tid] + 1e-8f);
    __syncthreads();

    const int tq = tid >> 4;   // 0..15 -> q group of 4
    const int td = tid & 15;   // 0..15 -> d group of 4

    float4 acc[4];
#pragma unroll
    for (int i = 0; i < 4; ++i) acc[i] = make_float4(0.f, 0.f, 0.f, 0.f);

    const int kk = tid & 63;   // column within 64-wide chunk
    const int r4 = tid >> 6;   // 0..3 row-group for staging

    for (int kc = 0; kc < KT; kc += 64) {
        // stage + scale + writeback attn chunk (coalesced: lanes vary kk)
#pragma unroll
        for (int qq = 0; qq < 64; qq += 4) {
            const int q = qq + r4;
            const size_t gi = ((size_t)(b * NQ + q)) * NK + (size_t)(k0 + kc + kk);
            const float p = attn[gi] * invs[q];
            attn[gi] = p;
            Ps[q][kk] = p;
        }
        // stage value chunk (coalesced: lanes vary d = kk)
#pragma unroll
        for (int kk2 = 0; kk2 < 64; kk2 += 4) {
            const int krow = kk2 + r4;
            Vs[krow][kk] = value[((size_t)b * NK + (size_t)(k0 + kc + krow)) * ND + kk];
        }
        __syncthreads();

#pragma unroll
        for (int k1 = 0; k1 < 64; ++k1) {
            const float4 vv = *reinterpret_cast<const float4*>(&Vs[k1][td * 4]);
#pragma unroll
            for (int qi = 0; qi < 4; ++qi) {
                const float pq = Ps[tq * 4 + qi][k1];
                acc[qi].x = fmaf(pq, vv.x, acc[qi].x);
                acc[qi].y = fmaf(pq, vv.y, acc[qi].y);
                acc[qi].z = fmaf(pq, vv.z, acc[qi].z);
                acc[qi].w = fmaf(pq, vv.w, acc[qi].w);
            }
        }
        __syncthreads();
    }

#pragma unroll
    for (int qi = 0; qi < 4; ++qi) {
        float* op = out + ((size_t)(b * NQ + tq * 4 + qi)) * ND + td * 4;
        atomicAdd(op + 0, acc[qi].x);
        atomicAdd(op + 1, acc[qi].y);
        atomicAdd(op + 2, acc[qi].z);
        atomicAdd(op + 3, acc[qi].w);
    }
}

extern "C" void kernel_launch(void* const* d_in, const int* in_sizes, int n_in,
                              void* d_out, int out_size, void* d_ws, size_t ws_size,
                              hipStream_t stream) {
    const float* query = (const float*)d_in[0];
    const float* key   = (const float*)d_in[1];
    const float* value = (const float*)d_in[2];

    float* out  = (float*)d_out;                      // [B,Q,D]   262144 floats
    float* attn = (float*)d_out + (size_t)NB * NQ * ND; // [B,Q,K] 33554432 floats
    float* rowsum = (float*)d_ws;                     // [B,Q]     4096 floats

    // zero accumulators each call (harness does not re-poison between replays)
    hipMemsetAsync(rowsum, 0, (size_t)NB * NQ * sizeof(float), stream);
    hipMemsetAsync(out, 0, (size_t)NB * NQ * ND * sizeof(float), stream);

    dim3 g1(NK / 256, NB);
    k_qk_softmax<<<g1, 256, 0, stream>>>(query, key, attn, rowsum);

    dim3 g2(NK / KT, NB);
    k_scale_pv<<<g2, 256, 0, stream>>>(value, rowsum, attn, out);
}

// Round 2
// 300.786 us; speedup vs baseline: 1.5127x; 1.5127x over previous
//
#include <hip/hip_runtime.h>
#include <cstddef>

#define NB 64
#define NQ 64
#define NK 8192
#define ND 64

// ---------------------------------------------------------------------------
// Kernel 1: per (b, 512-key tile). Each thread owns TWO key columns (k, k+256):
//   s[q] = dot(query[b,q,:], key[b,k,:])  (2x64 logits in registers)
//   p[q] = softmax over q of s[q]/8
//   attn[b,q,k] = p[q]  (unnormalized-over-k, fixed up by kernel 2)
//   rowsum[b,q] += pA+pB (wave-reduced, one atomic per wave per q)
// Query tile staged in LDS (16 KB); q-loop fully unrolled with STATIC indices
// so sA/sB stay in VGPRs (round-0 version spilled to scratch: VGPR=52).
// ---------------------------------------------------------------------------
__global__ __launch_bounds__(256, 2) void k_qk_softmax(
    const float* __restrict__ query,
    const float* __restrict__ key,
    float* __restrict__ attn,
    float* __restrict__ rowsum)
{
    __shared__ alignas(16) float Qs[NQ * ND];   // [q][d], 16 KB

    const int b   = blockIdx.y;
    const int tid = threadIdx.x;
    const int k0  = blockIdx.x * 512 + tid;     // this thread's keys: k0, k0+256

    // stage query[b] (1024 float4, 256 threads -> 4 each, coalesced)
    {
        const float4* qg = reinterpret_cast<const float4*>(query + (size_t)b * NQ * ND);
        float4* qs = reinterpret_cast<float4*>(Qs);
#pragma unroll
        for (int i = 0; i < 4; ++i) qs[tid + 256 * i] = qg[tid + 256 * i];
    }
    __syncthreads();

    const float* __restrict__ krA = key + ((size_t)b * NK + k0) * ND;
    const float* __restrict__ krB = krA + 256 * ND;

    float sA[NQ], sB[NQ];
#pragma unroll
    for (int q = 0; q < NQ; ++q) { sA[q] = 0.f; sB[q] = 0.f; }

    for (int d0 = 0; d0 < 16; ++d0) {          // runtime loop: body fits I-cache
        const float4 ka = *reinterpret_cast<const float4*>(krA + d0 * 4);
        const float4 kb = *reinterpret_cast<const float4*>(krB + d0 * 4);
#pragma unroll
        for (int q = 0; q < NQ; ++q) {          // static q -> sA/sB in registers
            const float4 qv = *reinterpret_cast<const float4*>(&Qs[q * ND + d0 * 4]);
            sA[q] = fmaf(ka.x, qv.x, fmaf(ka.y, qv.y, fmaf(ka.z, qv.z, fmaf(ka.w, qv.w, sA[q]))));
            sB[q] = fmaf(kb.x, qv.x, fmaf(kb.y, qv.y, fmaf(kb.z, qv.z, fmaf(kb.w, qv.w, sB[q]))));
        }
    }

    // softmax over q for each of the two key columns (scale 1/8 folded into exp)
    float mA = sA[0], mB = sB[0];
#pragma unroll
    for (int q = 1; q < NQ; ++q) { mA = fmaxf(mA, sA[q]); mB = fmaxf(mB, sB[q]); }
    float sumA = 0.f, sumB = 0.f;
#pragma unroll
    for (int q = 0; q < NQ; ++q) {
        sA[q] = __expf((sA[q] - mA) * 0.125f); sumA += sA[q];
        sB[q] = __expf((sB[q] - mB) * 0.125f); sumB += sB[q];
    }
    const float invA = 1.f / sumA;
    const float invB = 1.f / sumB;

    float* __restrict__ arow = attn + (size_t)b * NQ * NK + k0;
#pragma unroll
    for (int q = 0; q < NQ; ++q) {
        const float pA = sA[q] * invA;
        const float pB = sB[q] * invB;
        arow[(size_t)q * NK]       = pA;        // coalesced across lanes
        arow[(size_t)q * NK + 256] = pB;
        float v = pA + pB;                      // same (b,q) row -> one reduction
#pragma unroll
        for (int off = 32; off > 0; off >>= 1) v += __shfl_xor(v, off, 64);
        if ((tid & 63) == 0) atomicAdd(&rowsum[b * NQ + q], v);
    }
}

// ---------------------------------------------------------------------------
// Kernel 2: per (b, 512-key tile).
//   - load attn tile, scale by 1/(rowsum+eps), write back (final attn output)
//   - accumulate out[b,q,:] += sum_k p_hat[q,k] * value[b,k,:] via LDS tiles,
//     atomicAdd partial 64x64 result into zero-initialized out.
// ---------------------------------------------------------------------------
#define KT 512
__global__ __launch_bounds__(256) void k_scale_pv(
    const float* __restrict__ value,
    const float* __restrict__ rowsum,
    float* __restrict__ attn,
    float* __restrict__ out)
{
    __shared__ float Ps[64][65];   // [q][kk], +1 pad breaks q-strided read conflicts
    __shared__ float Vs[64][64];   // [kk][d]
    __shared__ float invs[NQ];

    const int b  = blockIdx.y;
    const int k0 = blockIdx.x * KT;
    const int tid = threadIdx.x;

    if (tid < NQ) invs[tid] = 1.f / (rowsum[b * NQ + tid] + 1e-8f);
    __syncthreads();

    const int tq = tid >> 4;   // 0..15 -> q group of 4
    const int td = tid & 15;   // 0..15 -> d group of 4

    float4 acc[4];
#pragma unroll
    for (int i = 0; i < 4; ++i) acc[i] = make_float4(0.f, 0.f, 0.f, 0.f);

    const int kk = tid & 63;   // column within 64-wide chunk
    const int r4 = tid >> 6;   // 0..3 row-group for staging

    for (int kc = 0; kc < KT; kc += 64) {
        // stage + scale + writeback attn chunk (coalesced: lanes vary kk)
#pragma unroll
        for (int qq = 0; qq < 64; qq += 4) {
            const int q = qq + r4;
            const size_t gi = ((size_t)(b * NQ + q)) * NK + (size_t)(k0 + kc + kk);
            const float p = attn[gi] * invs[q];
            attn[gi] = p;
            Ps[q][kk] = p;
        }
        // stage value chunk (coalesced: lanes vary d = kk)
#pragma unroll
        for (int kk2 = 0; kk2 < 64; kk2 += 4) {
            const int krow = kk2 + r4;
            Vs[krow][kk] = value[((size_t)b * NK + (size_t)(k0 + kc + krow)) * ND + kk];
        }
        __syncthreads();

#pragma unroll
        for (int k1 = 0; k1 < 64; ++k1) {
            const float4 vv = *reinterpret_cast<const float4*>(&Vs[k1][td * 4]);
#pragma unroll
            for (int qi = 0; qi < 4; ++qi) {
                const float pq = Ps[tq * 4 + qi][k1];
                acc[qi].x = fmaf(pq, vv.x, acc[qi].x);
                acc[qi].y = fmaf(pq, vv.y, acc[qi].y);
                acc[qi].z = fmaf(pq, vv.z, acc[qi].z);
                acc[qi].w = fmaf(pq, vv.w, acc[qi].w);
            }
        }
        __syncthreads();
    }

#pragma unroll
    for (int qi = 0; qi < 4; ++qi) {
        float* op = out + ((size_t)(b * NQ + tq * 4 + qi)) * ND + td * 4;
        atomicAdd(op + 0, acc[qi].x);
        atomicAdd(op + 1, acc[qi].y);
        atomicAdd(op + 2, acc[qi].z);
        atomicAdd(op + 3, acc[qi].w);
    }
}

extern "C" void kernel_launch(void* const* d_in, const int* in_sizes, int n_in,
                              void* d_out, int out_size, void* d_ws, size_t ws_size,
                              hipStream_t stream) {
    const float* query = (const float*)d_in[0];
    const float* key   = (const float*)d_in[1];
    const float* value = (const float*)d_in[2];

    float* out  = (float*)d_out;                        // [B,Q,D]   262144 floats
    float* attn = (float*)d_out + (size_t)NB * NQ * ND; // [B,Q,K] 33554432 floats
    float* rowsum = (float*)d_ws;                       // [B,Q]     4096 floats

    // zero accumulators each call (harness does not re-poison between replays)
    hipMemsetAsync(rowsum, 0, (size_t)NB * NQ * sizeof(float), stream);
    hipMemsetAsync(out, 0, (size_t)NB * NQ * ND * sizeof(float), stream);

    dim3 g1(NK / 512, NB);
    k_qk_softmax<<<g1, 256, 0, stream>>>(query, key, attn, rowsum);

    dim3 g2(NK / KT, NB);
    k_scale_pv<<<g2, 256, 0, stream>>>(value, rowsum, attn, out);
}